// Round 13
// baseline (9924.438 us; speedup 1.0000x reference)
//
#include <hip/hip_runtime.h>
#include <hip/hip_bf16.h>
#include <math.h>

#define V_  128
#define E_  512
#define H_  1024
#define NE_ 10
#define B_  32
#define S_  1024
#define G4H (4*H_)   // 4096

typedef short bf16x8 __attribute__((ext_vector_type(8)));
typedef float f32x4  __attribute__((ext_vector_type(4)));
typedef int   i32x4  __attribute__((ext_vector_type(4)));

__device__ __forceinline__ short f2bf(float f) {
    __hip_bfloat16 h = __float2bfloat16(f);
    short s; __builtin_memcpy(&s, &h, 2); return s;
}
__device__ __forceinline__ float bf2f(ushort u) {
    unsigned int x = ((unsigned int)u) << 16;
    float f; __builtin_memcpy(&f, &x, 4); return f;
}
__device__ __forceinline__ float sigf(float x) { return 1.f / (1.f + __expf(-x)); }
__device__ __forceinline__ float tanhfast(float x) { return 1.f - 2.f / (__expf(2.f * x) + 1.f); }

// ---- agent-scope (sc1) coherent ops — R10/R11-verified cross-XCD at the IC ----
__device__ __forceinline__ i32x4 gload4_sc(const void* p) {
    i32x4 r;
    asm volatile("global_load_dwordx4 %0, %1, off sc1" : "=&v"(r) : "v"(p));
    return r;
}
__device__ __forceinline__ void gstore4_sc(void* p, i32x4 v) {
    asm volatile("global_store_dwordx4 %0, %1, off sc1" :: "v"(p), "v"(v) : "memory");
}
// wait for loads AND pin the compiler (rule #18)
#define WAITCNT0() do { asm volatile("s_waitcnt vmcnt(0)" ::: "memory"); \
                        __builtin_amdgcn_sched_barrier(0); } while (0)

// ---------------- K1: T2[v][j*4+q] = emb[v] . W_ih[q*H+j] + b_ih[q*H+j] ----------------
__global__ __launch_bounds__(256) void build_T(
    const float* __restrict__ emb, const float* __restrict__ W_ih,
    const float* __restrict__ b_ih, float* __restrict__ T2)
{
    int idx = blockIdx.x * 256 + threadIdx.x;    // over 4096*128
    int g = idx >> 7, v = idx & 127;
    const float* er = emb + v * E_;
    const float* wr = W_ih + (size_t)g * E_;
    float acc = b_ih[g];
    #pragma unroll 4
    for (int e = 0; e < E_; ++e) acc += er[e] * wr[e];
    T2[v * G4H + (g & 1023) * 4 + (g >> 10)] = acc;   // [v][j][q] layout
}

// ---------------- K1b: We -> bf16 ----------------
__global__ __launch_bounds__(256) void conv_bf16(
    const float* __restrict__ src, ushort* __restrict__ dst, int n)
{
    int i = blockIdx.x * 256 + threadIdx.x;
    if (i < n) dst[i] = (ushort)f2bf(src[i]);
}

// ---------------- K2: persistent LSTM scan, 128 blocks x 512 thr, TAG-IN-DATA ----------------
// Compute structure = R11 (4.6ms, verified): block p owns units 8p..8p+7, W-slice
// in LDS (XOR-swizzled), wave (bh,kq) = batch-half x K-quarter, disjoint chunks.
// Sync = R9/R10's proven tag-in-data at sc1: published dword = bf16(h) | (t+1)<<16.
// Reader's data load IS the detection (no flag hop); producer store is
// fire-and-forget (no vmcnt drain, no flag store). Selective per-chunk retry.
__global__ __launch_bounds__(512) void lstm_scan(
    const int* __restrict__ x, const float* __restrict__ T2,
    const float* __restrict__ W_hh, const float* __restrict__ b_hh,
    unsigned int* __restrict__ tagbuf, ushort* __restrict__ h_all)
{
    const int p = blockIdx.x;            // 0..127
    const int tid = threadIdx.x;         // 0..511
    const int lane = tid & 63, wave = tid >> 6;
    const int m = lane & 15, kg = lane >> 4;
    const int bh = wave & 1, kq = wave >> 1;   // batch-half, K-quarter

    __shared__ __align__(16) ushort Wl[32 * 1024];   // 64KB swizzled W slice (R11 layout)
    __shared__ float  part[8 * 512];                 // 16KB wave partials
    __shared__ __align__(16) float pre_s[32][36];
    __shared__ __align__(16) ushort hstage[256];
    __shared__ float  bhh_l[32];

    // ---- stage W slice to LDS (once): row r -> W_hh[(r&3)*H + 8p + (r>>2)] ----
    #pragma unroll
    for (int i = 0; i < 8; ++i) {
        int grp = tid + i * 512;             // 4096 groups of 8 elems
        int r = grp >> 7, k8 = (grp & 127) * 8;
        const float* wsrc = W_hh + (size_t)((r & 3) * H_ + p * 8 + (r >> 2)) * H_ + k8;
        float4 w0 = *(const float4*)wsrc;
        float4 w1 = *(const float4*)(wsrc + 4);
        bf16x8 a;
        a[0]=f2bf(w0.x); a[1]=f2bf(w0.y); a[2]=f2bf(w0.z); a[3]=f2bf(w0.w);
        a[4]=f2bf(w1.x); a[5]=f2bf(w1.y); a[6]=f2bf(w1.z); a[7]=f2bf(w1.w);
        *(bf16x8*)&Wl[r * 1024 + (k8 ^ ((r & 7) << 3))] = a;
    }
    if (tid < 32) bhh_l[tid] = b_hh[(tid & 3) * H_ + p * 8 + (tid >> 2)];

    // chunk offsets (DWORDS): chunk c = kk*2+half at (bh*16+m)*1024 + kq*256
    // + kk*32 + kg*8 + half*4 — each 16B chunk lies inside ONE producer store.
    int off16[16];
    #pragma unroll
    for (int kk = 0; kk < 8; ++kk) {
        int base = (bh * 16 + m) * 1024 + kq * 256 + kk * 32 + kg * 8;
        off16[kk * 2]     = base;
        off16[kk * 2 + 1] = base + 4;
    }

    const int eb = tid >> 3, eu = tid & 7;   // epilogue mapping (tid<256)
    float cst = 0.f;
    unsigned int* tb0 = tagbuf;
    unsigned int* tb1 = tagbuf + 32 * 1024;
    const int swz = (m & 7) << 3;            // Wl read swizzle (R11)
    __syncthreads();

    for (int t = 0; t < S_; ++t) {
        const unsigned int* trd = (t & 1) ? tb0 : tb1;   // tags == t; t=0 -> zeroed tb1
        unsigned int*       twr = (t & 1) ? tb1 : tb0;   // publish tags t+1

        // ---- poll + load, selective retry: a chunk is ready when all 4 dwords
        //      carry tag t (tag > t impossible for a still-needed chunk) ----
        i32x4 braw[16];
        const unsigned int exp_tag = (unsigned int)t;
        unsigned int pend = 0xFFFFu;
        for (;;) {
            #pragma unroll
            for (int i = 0; i < 16; ++i)
                if (pend & (1u << i))
                    braw[i] = gload4_sc(trd + off16[i]);
            WAITCNT0();
            #pragma unroll
            for (int i = 0; i < 16; ++i)
                if (pend & (1u << i)) {
                    unsigned int bad = (((unsigned int)braw[i][0]) >> 16) ^ exp_tag;
                    bad |= (((unsigned int)braw[i][1]) >> 16) ^ exp_tag;
                    bad |= (((unsigned int)braw[i][2]) >> 16) ^ exp_tag;
                    bad |= (((unsigned int)braw[i][3]) >> 16) ^ exp_tag;
                    if (bad == 0) pend &= ~(1u << i);
                }
            if (__all(pend == 0)) break;
            __builtin_amdgcn_s_sleep(1);
        }

        // ---- prefetch gate-table rows (cached; hides under MFMA) ----
        int xv = 0; float4 tv = {0.f, 0.f, 0.f, 0.f};
        if (tid < 256) {
            xv = x[eb * S_ + t];
            tv = *(const float4*)(T2 + (size_t)xv * G4H + (size_t)(p * 8 + eu) * 4);
        }

        // ---- unpack + MFMA: 2 row-tiles (A from LDS) x 8 kk over K-quarter ----
        f32x4 acc0 = {0.f,0.f,0.f,0.f}, acc1 = {0.f,0.f,0.f,0.f};
        #pragma unroll
        for (int kk = 0; kk < 8; ++kk) {
            i32x4 lo = braw[kk * 2], hi = braw[kk * 2 + 1];
            i32x4 fv;
            fv[0] = (lo[0] & 0xFFFF) | (lo[1] << 16);
            fv[1] = (lo[2] & 0xFFFF) | (lo[3] << 16);
            fv[2] = (hi[0] & 0xFFFF) | (hi[1] << 16);
            fv[3] = (hi[2] & 0xFFFF) | (hi[3] << 16);
            bf16x8 bv; __builtin_memcpy(&bv, &fv, 16);
            int koff = (kq * 256 + kk * 32 + kg * 8) ^ swz;
            bf16x8 a0 = *(const bf16x8*)&Wl[m * 1024 + koff];          // tile0 row m
            bf16x8 a1 = *(const bf16x8*)&Wl[(16 + m) * 1024 + koff];   // tile1 row 16+m
            acc0 = __builtin_amdgcn_mfma_f32_16x16x32_bf16(a0, bv, acc0, 0, 0, 0);
            acc1 = __builtin_amdgcn_mfma_f32_16x16x32_bf16(a1, bv, acc1, 0, 0, 0);
        }
        // D: row16 = kg*4+d, col(batch) = m
        {
            float* pw = part + wave * 512;
            #pragma unroll
            for (int d = 0; d < 4; ++d) {
                pw[(kg * 4 + d) * 16 + m]       = acc0[d];
                pw[256 + (kg * 4 + d) * 16 + m] = acc1[d];
            }
        }
        __syncthreads();

        // ---- reduce over kq: flat = bh*512 + tile*256 + row16*16 + m ----
        #pragma unroll
        for (int i = 0; i < 2; ++i) {
            int flat = tid + i * 512;
            float s = part[flat] + part[1024 + flat] + part[2048 + flat] + part[3072 + flat];
            int b = ((flat >> 9) & 1) * 16 + (flat & 15);
            int r = ((flat >> 8) & 1) * 16 + ((flat >> 4) & 15);
            pre_s[b][r] = s;
        }
        __syncthreads();

        // ---- epilogue: thread = (batch eb, unit eu), c in register ----
        if (tid < 256) {
            float4 pv = *(const float4*)&pre_s[eb][eu * 4];
            int r0 = eu * 4;
            float pi = pv.x + tv.x + bhh_l[r0 + 0];
            float pf = pv.y + tv.y + bhh_l[r0 + 1];
            float pg = pv.z + tv.z + bhh_l[r0 + 2];
            float po = pv.w + tv.w + bhh_l[r0 + 3];
            cst = sigf(pf) * cst + sigf(pi) * tanhfast(pg);
            float h = sigf(po) * tanhfast(cst);
            unsigned int hb16 = (unsigned int)(unsigned short)f2bf(h);
            unsigned int hn = (unsigned int)__shfl_xor((int)hb16, 1);
            if (!(eu & 1))
                *(unsigned int*)(h_all + (size_t)eb * (S_ * H_) + (size_t)t * H_ + (p * 8 + eu))
                    = hb16 | (hn << 16);
            hstage[tid] = (ushort)hb16;        // hstage[eb*8+eu]
        }
        __syncthreads();                       // hstage complete

        if (t == S_ - 1) break;

        // ---- tagged publish (wave0, lanes 0-31 = one batch each): 8 dwords =
        //      bf16|tag, two 16B stores, FIRE-AND-FORGET (no drain, no flag) ----
        if (wave == 0 && lane < 32) {
            const ushort* hs8 = &hstage[lane * 8];
            unsigned int tg = ((unsigned int)(t + 1)) << 16;
            i32x4 v0, v1;
            v0[0] = (int)(hs8[0] | tg); v0[1] = (int)(hs8[1] | tg);
            v0[2] = (int)(hs8[2] | tg); v0[3] = (int)(hs8[3] | tg);
            v1[0] = (int)(hs8[4] | tg); v1[1] = (int)(hs8[5] | tg);
            v1[2] = (int)(hs8[6] | tg); v1[3] = (int)(hs8[7] | tg);
            unsigned int* dst = twr + lane * 1024 + p * 8;
            gstore4_sc(dst, v0);
            gstore4_sc(dst + 4, v1);
        }
        // no barrier: next step's data poll IS the synchronization
    }
}

// ---------------- K3: expert GEMM (bf16 MFMA)  C = A . Bw^T + be ----------------
__global__ __launch_bounds__(256) void expert_gemm(
    const ushort* __restrict__ A, const ushort* __restrict__ Bw,
    const float* __restrict__ be, float* __restrict__ out)
{
    __shared__ ushort As[128][40];
    __shared__ ushort Bs[128][40];
    const int tid = threadIdx.x;
    const int bm = blockIdx.x / 10, bn = blockIdx.x % 10;
    const int m0 = bm * 128, n0 = bn * 128;
    const int lane = tid & 63, wave = tid >> 6;
    const int wm = wave >> 1, wn = wave & 1;
    const int fm = lane & 15, kg = lane >> 4;

    const int srow = tid >> 1, scol = (tid & 1) * 16;
    const ushort* Ag = A  + (size_t)(m0 + srow) * H_ + scol;
    const ushort* Bg = Bw + (size_t)(n0 + srow) * H_ + scol;

    f32x4 acc[4][4];
    #pragma unroll
    for (int i = 0; i < 4; ++i)
        #pragma unroll
        for (int j = 0; j < 4; ++j) acc[i][j] = (f32x4){0.f,0.f,0.f,0.f};

    int4 ra0 = *(const int4*)(Ag),     ra1 = *(const int4*)(Ag + 8);
    int4 rb0 = *(const int4*)(Bg),     rb1 = *(const int4*)(Bg + 8);

    for (int k0 = 0; k0 < H_; k0 += 32) {
        __syncthreads();
        *(int4*)&As[srow][scol] = ra0;  *(int4*)&As[srow][scol + 8] = ra1;
        *(int4*)&Bs[srow][scol] = rb0;  *(int4*)&Bs[srow][scol + 8] = rb1;
        __syncthreads();
        if (k0 + 32 < H_) {
            ra0 = *(const int4*)(Ag + k0 + 32);  ra1 = *(const int4*)(Ag + k0 + 40);
            rb0 = *(const int4*)(Bg + k0 + 32);  rb1 = *(const int4*)(Bg + k0 + 40);
        }
        bf16x8 af[4], bfv[4];
        #pragma unroll
        for (int i = 0; i < 4; ++i) af[i] = *(const bf16x8*)&As[wm * 64 + i * 16 + fm][kg * 8];
        #pragma unroll
        for (int j = 0; j < 4; ++j) bfv[j] = *(const bf16x8*)&Bs[wn * 64 + j * 16 + fm][kg * 8];
        #pragma unroll
        for (int i = 0; i < 4; ++i)
            #pragma unroll
            for (int j = 0; j < 4; ++j)
                acc[i][j] = __builtin_amdgcn_mfma_f32_16x16x32_bf16(af[i], bfv[j], acc[i][j], 0, 0, 0);
    }

    const int e = bn;
    const size_t ebase = (size_t)e * ((size_t)B_ * S_ * V_);
    #pragma unroll
    for (int i = 0; i < 4; ++i) {
        #pragma unroll
        for (int d = 0; d < 4; ++d) {
            int row = m0 + wm * 64 + i * 16 + kg * 4 + d;
            float* orow = out + ebase + (size_t)row * V_;
            #pragma unroll
            for (int j = 0; j < 4; ++j) {
                int col = wn * 64 + j * 16 + fm;
                orow[col] = acc[i][j][d] + be[n0 + col];
            }
        }
    }
}

// ---------------- K4: gating softmax (bf16 h) ----------------
__global__ __launch_bounds__(256) void gating_kernel(
    const ushort* __restrict__ h_all, const float* __restrict__ Wg,
    const float* __restrict__ bg, float* __restrict__ gate_out)
{
    int b = blockIdx.x;
    int tid = threadIdx.x;
    __shared__ float red[NE_][256];
    const ushort* h = h_all + (size_t)b * (S_ * H_) + (size_t)(S_ - 1) * H_;
    float pa[NE_];
    #pragma unroll
    for (int e = 0; e < NE_; ++e) pa[e] = 0.f;
    for (int k = tid; k < H_; k += 256) {
        float hv = bf2f(h[k]);
        #pragma unroll
        for (int e = 0; e < NE_; ++e) pa[e] += hv * Wg[e * H_ + k];
    }
    #pragma unroll
    for (int e = 0; e < NE_; ++e) red[e][tid] = pa[e];
    __syncthreads();
    for (int s = 128; s > 0; s >>= 1) {
        if (tid < s) {
            #pragma unroll
            for (int e = 0; e < NE_; ++e) red[e][tid] += red[e][tid + s];
        }
        __syncthreads();
    }
    if (tid == 0) {
        float lg[NE_], mx = -1e30f;
        #pragma unroll
        for (int e = 0; e < NE_; ++e) { lg[e] = red[e][0] + bg[e]; mx = fmaxf(mx, lg[e]); }
        float s = 0.f;
        #pragma unroll
        for (int e = 0; e < NE_; ++e) { lg[e] = expf(lg[e] - mx); s += lg[e]; }
        #pragma unroll
        for (int e = 0; e < NE_; ++e) gate_out[b * NE_ + e] = lg[e] / s;
    }
}

// ---------------- K5: combine ----------------
__global__ __launch_bounds__(256) void combine_kernel(
    const float* __restrict__ exp_out, const float* __restrict__ gate,
    float* __restrict__ comb)
{
    int idx = blockIdx.x * 256 + threadIdx.x;  // < 4194304
    int b = idx >> 17;
    float acc = 0.f;
    #pragma unroll
    for (int e = 0; e < NE_; ++e)
        acc += gate[b * NE_ + e] * exp_out[(size_t)e * (size_t)(B_ * S_ * V_) + idx];
    comb[idx] = acc;
}

extern "C" void kernel_launch(void* const* d_in, const int* in_sizes, int n_in,
                              void* d_out, int out_size, void* d_ws, size_t ws_size,
                              hipStream_t stream)
{
    const int*   x    = (const int*)  d_in[0];
    const float* emb  = (const float*)d_in[1];
    const float* W_ih = (const float*)d_in[2];
    const float* W_hh = (const float*)d_in[3];
    const float* b_ih = (const float*)d_in[4];
    const float* b_hh = (const float*)d_in[5];
    const float* We   = (const float*)d_in[6];
    const float* be   = (const float*)d_in[7];
    const float* Wg   = (const float*)d_in[8];
    const float* bg   = (const float*)d_in[9];

    float* out     = (float*)d_out;
    float* comb    = out;                               // [B,S,V]
    float* exp_out = out + 4194304;                     // [NE,B,S,V]
    float* gate    = out + 4194304 + 41943040;          // [B,NE]

    char*         ws     = (char*)d_ws;
    float*        T2     = (float*)ws;                          // 2 MB
    unsigned int* tagbuf = (unsigned int*)(ws + (2u << 20));    // 2 x 128 KB tagged h
    ushort*       We_bf  = (ushort*)(ws + (4u << 20));          // 2.6 MB
    ushort*       h_all  = (ushort*)(ws + (8u << 20));          // 67 MB [B,S,H] bf16

    // zero tag buffers: tag 0 == "h_{-1}=0 published" — required every replay
    (void)hipMemsetAsync(ws + (2u << 20), 0, (256u << 10), stream);

    build_T      <<<2048, 256, 0, stream>>>(emb, W_ih, b_ih, T2);
    conv_bf16    <<<(NE_ * V_ * H_ + 255) / 256, 256, 0, stream>>>(We, We_bf, NE_ * V_ * H_);
    lstm_scan    <<<128, 512, 0, stream>>>(x, T2, W_hh, b_hh, tagbuf, h_all);
    expert_gemm  <<<256 * 10, 256, 0, stream>>>(h_all, We_bf, be, exp_out);
    gating_kernel<<<B_, 256, 0, stream>>>(h_all, Wg, bg, gate);
    combine_kernel<<<4194304 / 256, 256, 0, stream>>>(exp_out, gate, comb);
}

// Round 14
// 4946.874 us; speedup vs baseline: 2.0062x; 2.0062x over previous
//
#include <hip/hip_runtime.h>
#include <hip/hip_bf16.h>
#include <math.h>

#define V_  128
#define E_  512
#define H_  1024
#define NE_ 10
#define B_  32
#define S_  1024
#define G4H (4*H_)   // 4096

typedef short bf16x8 __attribute__((ext_vector_type(8)));
typedef float f32x4  __attribute__((ext_vector_type(4)));
typedef int   i32x4  __attribute__((ext_vector_type(4)));

__device__ __forceinline__ short f2bf(float f) {
    __hip_bfloat16 h = __float2bfloat16(f);
    short s; __builtin_memcpy(&s, &h, 2); return s;
}
__device__ __forceinline__ float bf2f(ushort u) {
    unsigned int x = ((unsigned int)u) << 16;
    float f; __builtin_memcpy(&f, &x, 4); return f;
}
__device__ __forceinline__ float sigf(float x) { return 1.f / (1.f + __expf(-x)); }
__device__ __forceinline__ float tanhfast(float x) { return 1.f - 2.f / (__expf(2.f * x) + 1.f); }

// ---- agent-scope (sc1) coherent ops — R10/R11-verified cross-XCD at the IC ----
__device__ __forceinline__ i32x4 gload4_sc(const void* p) {
    i32x4 r;
    asm volatile("global_load_dwordx4 %0, %1, off sc1" : "=&v"(r) : "v"(p));
    return r;
}
__device__ __forceinline__ void gstore4_sc(void* p, i32x4 v) {
    asm volatile("global_store_dwordx4 %0, %1, off sc1" :: "v"(p), "v"(v) : "memory");
}
__device__ __forceinline__ void gstore1_sc(void* p, int v) {
    asm volatile("global_store_dword %0, %1, off sc1" :: "v"(p), "v"(v) : "memory");
}
// wait for loads AND pin the compiler (rule #18)
#define WAITCNT0() do { asm volatile("s_waitcnt vmcnt(0)" ::: "memory"); \
                        __builtin_amdgcn_sched_barrier(0); } while (0)

// ---------------- K1: T2[v][j*4+q] = emb[v] . W_ih[q*H+j] + b_ih[q*H+j] ----------------
__global__ __launch_bounds__(256) void build_T(
    const float* __restrict__ emb, const float* __restrict__ W_ih,
    const float* __restrict__ b_ih, float* __restrict__ T2)
{
    int idx = blockIdx.x * 256 + threadIdx.x;    // over 4096*128
    int g = idx >> 7, v = idx & 127;
    const float* er = emb + v * E_;
    const float* wr = W_ih + (size_t)g * E_;
    float acc = b_ih[g];
    #pragma unroll 4
    for (int e = 0; e < E_; ++e) acc += er[e] * wr[e];
    T2[v * G4H + (g & 1023) * 4 + (g >> 10)] = acc;   // [v][j][q] layout
}

// ---------------- K1b: We -> bf16 ----------------
__global__ __launch_bounds__(256) void conv_bf16(
    const float* __restrict__ src, ushort* __restrict__ dst, int n)
{
    int i = blockIdx.x * 256 + threadIdx.x;
    if (i < n) dst[i] = (ushort)f2bf(src[i]);
}

// ---------------- K2: persistent LSTM scan, 128 blocks x 512 thr (R11, verified) ----------------
// Block p owns units 8p..8p+7 (32 gate rows). W-slice (64KB bf16) lives in LDS,
// XOR-swizzled. Wave w = (bh=w&1, kq=w>>1): 32 rows x 16 batches x K-quarter;
// B-chunks disjoint across waves (64KB/block/step total). Protocol: per-wave poll
// of its 32 source flags, sc1 exchange, 16B chunks == producers' atomic stores,
// publish+ack+flag by wave0.
__global__ __launch_bounds__(512) void lstm_scan(
    const int* __restrict__ x, const float* __restrict__ T2,
    const float* __restrict__ W_hh, const float* __restrict__ b_hh,
    ushort* __restrict__ hbuf, ushort* __restrict__ h_all, int* __restrict__ flags)
{
    const int p = blockIdx.x;            // 0..127
    const int tid = threadIdx.x;         // 0..511
    const int lane = tid & 63, wave = tid >> 6;
    const int m = lane & 15, kg = lane >> 4;
    const int bh = wave & 1, kq = wave >> 1;   // batch-half, K-quarter

    __shared__ __align__(16) ushort Wl[32 * 1024];   // 64KB swizzled W slice
    __shared__ float  part[8 * 512];                 // 16KB wave partials
    __shared__ __align__(16) float pre_s[32][36];
    __shared__ __align__(16) ushort hstage[256];
    __shared__ float  bhh_l[32];

    // ---- stage W slice to LDS (once): row r -> W_hh[(r&3)*H + 8p + (r>>2)] ----
    #pragma unroll
    for (int i = 0; i < 8; ++i) {
        int grp = tid + i * 512;             // 4096 groups of 8 elems
        int r = grp >> 7, k8 = (grp & 127) * 8;
        const float* wsrc = W_hh + (size_t)((r & 3) * H_ + p * 8 + (r >> 2)) * H_ + k8;
        float4 w0 = *(const float4*)wsrc;
        float4 w1 = *(const float4*)(wsrc + 4);
        bf16x8 a;
        a[0]=f2bf(w0.x); a[1]=f2bf(w0.y); a[2]=f2bf(w0.z); a[3]=f2bf(w0.w);
        a[4]=f2bf(w1.x); a[5]=f2bf(w1.y); a[6]=f2bf(w1.z); a[7]=f2bf(w1.w);
        *(bf16x8*)&Wl[r * 1024 + (k8 ^ ((r & 7) << 3))] = a;
    }
    if (tid < 32) bhh_l[tid] = b_hh[(tid & 3) * H_ + p * 8 + (tid >> 2)];

    // B-chunk offsets (ushorts): each 16B chunk == one producer's 16B store
    int boff[8];
    #pragma unroll
    for (int kk = 0; kk < 8; ++kk)
        boff[kk] = (bh * 16 + m) * 1024 + kq * 256 + kk * 32 + kg * 8;

    const int eb = tid >> 3, eu = tid & 7;   // epilogue mapping (tid<256)
    float cst = 0.f;
    ushort* hb0 = hbuf;
    ushort* hb1 = hbuf + B_ * H_;
    const int swz = (m & 7) << 3;            // same for rows m and 16+m
    __syncthreads();

    for (int t = 0; t < S_; ++t) {
        const ushort* hrd = (t & 1) ? hb0 : hb1;   // h_{t-1}; t=0 -> zeroed hb1
        ushort*       hwr = (t & 1) ? hb1 : hb0;

        // ---- poll my K-quarter's 32 source flags (blocks kq*32..+32) ----
        {
            const int src = kq * 32 + (lane & 31);
            const int* fp = flags + src * 16;
            for (;;) {
                int f;
                asm volatile("global_load_dword %0, %1, off sc1\n\ts_waitcnt vmcnt(0)"
                             : "=&v"(f) : "v"(fp) : "memory");
                __builtin_amdgcn_sched_barrier(0);
                if (__all(f >= t)) break;
                __builtin_amdgcn_s_sleep(1);
            }
        }

        // ---- load my 8 disjoint B-chunks ----
        i32x4 braw[8];
        #pragma unroll
        for (int kk = 0; kk < 8; ++kk) braw[kk] = gload4_sc(hrd + boff[kk]);
        WAITCNT0();

        // ---- MFMA: 2 row-tiles (A from LDS) x 8 kk over K-quarter ----
        f32x4 acc0 = {0.f,0.f,0.f,0.f}, acc1 = {0.f,0.f,0.f,0.f};
        #pragma unroll
        for (int kk = 0; kk < 8; ++kk) {
            int koff = (kq * 256 + kk * 32 + kg * 8) ^ swz;
            bf16x8 a0 = *(const bf16x8*)&Wl[m * 1024 + koff];          // tile0 row m
            bf16x8 a1 = *(const bf16x8*)&Wl[(16 + m) * 1024 + koff];   // tile1 row 16+m
            bf16x8 bv; __builtin_memcpy(&bv, &braw[kk], 16);
            acc0 = __builtin_amdgcn_mfma_f32_16x16x32_bf16(a0, bv, acc0, 0, 0, 0);
            acc1 = __builtin_amdgcn_mfma_f32_16x16x32_bf16(a1, bv, acc1, 0, 0, 0);
        }
        // D: row16 = kg*4+d, col(batch) = m; part idx = wave*512 + tile*256 + row16*16 + m
        {
            float* pw = part + wave * 512;
            #pragma unroll
            for (int d = 0; d < 4; ++d) {
                pw[(kg * 4 + d) * 16 + m]       = acc0[d];
                pw[256 + (kg * 4 + d) * 16 + m] = acc1[d];
            }
        }
        __syncthreads();

        // ---- reduce over kq: flat = bh*512 + tile*256 + row16*16 + m ----
        #pragma unroll
        for (int i = 0; i < 2; ++i) {
            int flat = tid + i * 512;
            float s = part[flat] + part[1024 + flat] + part[2048 + flat] + part[3072 + flat];
            int b = ((flat >> 9) & 1) * 16 + (flat & 15);
            int r = ((flat >> 8) & 1) * 16 + ((flat >> 4) & 15);
            pre_s[b][r] = s;
        }
        __syncthreads();

        // ---- epilogue: thread = (batch eb, unit eu), c in register ----
        if (tid < 256) {
            int xv = x[eb * S_ + t];
            float4 tv = *(const float4*)(T2 + (size_t)xv * G4H + (size_t)(p * 8 + eu) * 4);
            float4 pv = *(const float4*)&pre_s[eb][eu * 4];
            int r0 = eu * 4;
            float pi = pv.x + tv.x + bhh_l[r0 + 0];
            float pf = pv.y + tv.y + bhh_l[r0 + 1];
            float pg = pv.z + tv.z + bhh_l[r0 + 2];
            float po = pv.w + tv.w + bhh_l[r0 + 3];
            cst = sigf(pf) * cst + sigf(pi) * tanhfast(pg);
            float h = sigf(po) * tanhfast(cst);
            unsigned int hb16 = (unsigned int)(unsigned short)f2bf(h);
            unsigned int hn = (unsigned int)__shfl_xor((int)hb16, 1);
            if (!(eu & 1))
                *(unsigned int*)(h_all + (size_t)eb * (S_ * H_) + (size_t)t * H_ + (p * 8 + eu))
                    = hb16 | (hn << 16);
            hstage[tid] = (ushort)hb16;        // hstage[eb*8+eu] == hstage[tid]
        }
        __syncthreads();                       // hstage complete

        if (t == S_ - 1) break;

        // ---- publish 512B + flag (wave0); others run ahead to next poll ----
        if (wave == 0) {
            if (lane < 32) {
                i32x4 v = *(const i32x4*)&hstage[lane * 8];
                gstore4_sc(hwr + lane * 1024 + p * 8, v);   // 16B = this block's 8 units
            }
            asm volatile("s_waitcnt vmcnt(0)" ::: "memory"); // h_t at coherence point
            if (lane == 0) gstore1_sc(flags + p * 16, t + 1);
        }
    }
}

// ---------------- K3: expert GEMM (bf16 MFMA)  C = A . Bw^T + be ----------------
__global__ __launch_bounds__(256) void expert_gemm(
    const ushort* __restrict__ A, const ushort* __restrict__ Bw,
    const float* __restrict__ be, float* __restrict__ out)
{
    __shared__ ushort As[128][40];
    __shared__ ushort Bs[128][40];
    const int tid = threadIdx.x;
    const int bm = blockIdx.x / 10, bn = blockIdx.x % 10;
    const int m0 = bm * 128, n0 = bn * 128;
    const int lane = tid & 63, wave = tid >> 6;
    const int wm = wave >> 1, wn = wave & 1;
    const int fm = lane & 15, kg = lane >> 4;

    const int srow = tid >> 1, scol = (tid & 1) * 16;
    const ushort* Ag = A  + (size_t)(m0 + srow) * H_ + scol;
    const ushort* Bg = Bw + (size_t)(n0 + srow) * H_ + scol;

    f32x4 acc[4][4];
    #pragma unroll
    for (int i = 0; i < 4; ++i)
        #pragma unroll
        for (int j = 0; j < 4; ++j) acc[i][j] = (f32x4){0.f,0.f,0.f,0.f};

    int4 ra0 = *(const int4*)(Ag),     ra1 = *(const int4*)(Ag + 8);
    int4 rb0 = *(const int4*)(Bg),     rb1 = *(const int4*)(Bg + 8);

    for (int k0 = 0; k0 < H_; k0 += 32) {
        __syncthreads();
        *(int4*)&As[srow][scol] = ra0;  *(int4*)&As[srow][scol + 8] = ra1;
        *(int4*)&Bs[srow][scol] = rb0;  *(int4*)&Bs[srow][scol + 8] = rb1;
        __syncthreads();
        if (k0 + 32 < H_) {
            ra0 = *(const int4*)(Ag + k0 + 32);  ra1 = *(const int4*)(Ag + k0 + 40);
            rb0 = *(const int4*)(Bg + k0 + 32);  rb1 = *(const int4*)(Bg + k0 + 40);
        }
        bf16x8 af[4], bfv[4];
        #pragma unroll
        for (int i = 0; i < 4; ++i) af[i] = *(const bf16x8*)&As[wm * 64 + i * 16 + fm][kg * 8];
        #pragma unroll
        for (int j = 0; j < 4; ++j) bfv[j] = *(const bf16x8*)&Bs[wn * 64 + j * 16 + fm][kg * 8];
        #pragma unroll
        for (int i = 0; i < 4; ++i)
            #pragma unroll
            for (int j = 0; j < 4; ++j)
                acc[i][j] = __builtin_amdgcn_mfma_f32_16x16x32_bf16(af[i], bfv[j], acc[i][j], 0, 0, 0);
    }

    const int e = bn;
    const size_t ebase = (size_t)e * ((size_t)B_ * S_ * V_);
    #pragma unroll
    for (int i = 0; i < 4; ++i) {
        #pragma unroll
        for (int d = 0; d < 4; ++d) {
            int row = m0 + wm * 64 + i * 16 + kg * 4 + d;
            float* orow = out + ebase + (size_t)row * V_;
            #pragma unroll
            for (int j = 0; j < 4; ++j) {
                int col = wn * 64 + j * 16 + fm;
                orow[col] = acc[i][j][d] + be[n0 + col];
            }
        }
    }
}

// ---------------- K4: gating softmax (bf16 h) ----------------
__global__ __launch_bounds__(256) void gating_kernel(
    const ushort* __restrict__ h_all, const float* __restrict__ Wg,
    const float* __restrict__ bg, float* __restrict__ gate_out)
{
    int b = blockIdx.x;
    int tid = threadIdx.x;
    __shared__ float red[NE_][256];
    const ushort* h = h_all + (size_t)b * (S_ * H_) + (size_t)(S_ - 1) * H_;
    float pa[NE_];
    #pragma unroll
    for (int e = 0; e < NE_; ++e) pa[e] = 0.f;
    for (int k = tid; k < H_; k += 256) {
        float hv = bf2f(h[k]);
        #pragma unroll
        for (int e = 0; e < NE_; ++e) pa[e] += hv * Wg[e * H_ + k];
    }
    #pragma unroll
    for (int e = 0; e < NE_; ++e) red[e][tid] = pa[e];
    __syncthreads();
    for (int s = 128; s > 0; s >>= 1) {
        if (tid < s) {
            #pragma unroll
            for (int e = 0; e < NE_; ++e) red[e][tid] += red[e][tid + s];
        }
        __syncthreads();
    }
    if (tid == 0) {
        float lg[NE_], mx = -1e30f;
        #pragma unroll
        for (int e = 0; e < NE_; ++e) { lg[e] = red[e][0] + bg[e]; mx = fmaxf(mx, lg[e]); }
        float s = 0.f;
        #pragma unroll
        for (int e = 0; e < NE_; ++e) { lg[e] = expf(lg[e] - mx); s += lg[e]; }
        #pragma unroll
        for (int e = 0; e < NE_; ++e) gate_out[b * NE_ + e] = lg[e] / s;
    }
}

// ---------------- K5: combine ----------------
__global__ __launch_bounds__(256) void combine_kernel(
    const float* __restrict__ exp_out, const float* __restrict__ gate,
    float* __restrict__ comb)
{
    int idx = blockIdx.x * 256 + threadIdx.x;  // < 4194304
    int b = idx >> 17;
    float acc = 0.f;
    #pragma unroll
    for (int e = 0; e < NE_; ++e)
        acc += gate[b * NE_ + e] * exp_out[(size_t)e * (size_t)(B_ * S_ * V_) + idx];
    comb[idx] = acc;
}

extern "C" void kernel_launch(void* const* d_in, const int* in_sizes, int n_in,
                              void* d_out, int out_size, void* d_ws, size_t ws_size,
                              hipStream_t stream)
{
    const int*   x    = (const int*)  d_in[0];
    const float* emb  = (const float*)d_in[1];
    const float* W_ih = (const float*)d_in[2];
    const float* W_hh = (const float*)d_in[3];
    const float* b_ih = (const float*)d_in[4];
    const float* b_hh = (const float*)d_in[5];
    const float* We   = (const float*)d_in[6];
    const float* be   = (const float*)d_in[7];
    const float* Wg   = (const float*)d_in[8];
    const float* bg   = (const float*)d_in[9];

    float* out     = (float*)d_out;
    float* comb    = out;                               // [B,S,V]
    float* exp_out = out + 4194304;                     // [NE,B,S,V]
    float* gate    = out + 4194304 + 41943040;          // [B,NE]

    char*   ws    = (char*)d_ws;
    float*  T2    = (float*)ws;                               // 2 MB
    ushort* hbuf  = (ushort*)(ws + (2u << 20));               // 2 x 64 KB bf16
    int*    flags = (int*)   (ws + (2u << 20) + (128u << 10));// 128 x 64B slots = 8 KB
    ushort* We_bf = (ushort*)(ws + (4u << 20));               // 2.6 MB
    ushort* h_all = (ushort*)(ws + (8u << 20));               // 67 MB [B,S,H] bf16

    // zero h double-buffer (h0 = 0) and flags — required every replay
    (void)hipMemsetAsync(ws + (2u << 20), 0, (136u << 10), stream);

    build_T      <<<2048, 256, 0, stream>>>(emb, W_ih, b_ih, T2);
    conv_bf16    <<<(NE_ * V_ * H_ + 255) / 256, 256, 0, stream>>>(We, We_bf, NE_ * V_ * H_);
    lstm_scan    <<<128, 512, 0, stream>>>(x, T2, W_hh, b_hh, hbuf, h_all, flags);
    expert_gemm  <<<256 * 10, 256, 0, stream>>>(h_all, We_bf, be, exp_out);
    gating_kernel<<<B_, 256, 0, stream>>>(h_all, Wg, bg, gate);
    combine_kernel<<<4194304 / 256, 256, 0, stream>>>(exp_out, gate, comb);
}